// Round 1
// baseline (1256.148 us; speedup 1.0000x reference)
//
#include <hip/hip_runtime.h>

#define NPG 286
#define EPG 4000
#define FD 3
#define NF (NPG * FD)          // 858
#define NTHREADS 256

__device__ __forceinline__ void gconv_layer(
    const unsigned int* __restrict__ s_edge,
    const float* __restrict__ s_nout,
    const float* __restrict__ s_nin,
    float* __restrict__ s_x,        // in: x, out: relu(gconv(x))
    float* __restrict__ s_agg,
    const float* w, const float* bb, int t)
{
    // zero accumulators
    for (int i = t; i < NF; i += NTHREADS) s_agg[i] = 0.f;
    __syncthreads();
    // scatter: agg[dst] += x[src] * norm_out[src]
    for (int i = t; i < EPG; i += NTHREADS) {
        unsigned int e = s_edge[i];
        int s = (int)(e >> 16), d = (int)(e & 0xffffu);
        float no = s_nout[s];
        atomicAdd(&s_agg[d * 3 + 0], s_x[s * 3 + 0] * no);
        atomicAdd(&s_agg[d * 3 + 1], s_x[s * 3 + 1] * no);
        atomicAdd(&s_agg[d * 3 + 2], s_x[s * 3 + 2] * no);
    }
    __syncthreads();
    // per-node: agg * norm_in, 3x3 matmul + bias, relu
    for (int v = t; v < NPG; v += NTHREADS) {
        float ni = s_nin[v];
        float a0 = s_agg[v * 3 + 0] * ni;
        float a1 = s_agg[v * 3 + 1] * ni;
        float a2 = s_agg[v * 3 + 2] * ni;
        float o0 = fmaf(a0, w[0], fmaf(a1, w[3], fmaf(a2, w[6], bb[0])));
        float o1 = fmaf(a0, w[1], fmaf(a1, w[4], fmaf(a2, w[7], bb[1])));
        float o2 = fmaf(a0, w[2], fmaf(a1, w[5], fmaf(a2, w[8], bb[2])));
        s_x[v * 3 + 0] = fmaxf(o0, 0.f);
        s_x[v * 3 + 1] = fmaxf(o1, 0.f);
        s_x[v * 3 + 2] = fmaxf(o2, 0.f);
    }
    __syncthreads();
}

__global__ __launch_bounds__(NTHREADS) void ppi_fused_kernel(
    const float* __restrict__ feat,
    const int* __restrict__ src,
    const int* __restrict__ dst,
    const float* __restrict__ W1, const float* __restrict__ b1,
    const float* __restrict__ W2, const float* __restrict__ b2,
    const float* __restrict__ Wfc, const float* __restrict__ bfc,
    float* __restrict__ out)
{
    __shared__ unsigned int s_edge[EPG];   // 16000 B: (src_local<<16)|dst_local
    __shared__ float s_x[NF];              // 3432 B
    __shared__ float s_agg[NF];            // 3432 B
    __shared__ float s_nout[NPG];          // 1144 B
    __shared__ float s_nin[NPG];           // 1144 B
    __shared__ int s_deg[2 * NPG];         // 2288 B  [0..NPG) = out, [NPG..) = in
    __shared__ float s_red[NTHREADS / 64];

    const int b = blockIdx.x;
    const int t = threadIdx.x;
    const long long eb = (long long)b * EPG;
    const int nb = b * NPG;

    // init degree counters + load this graph's features
    for (int i = t; i < 2 * NPG; i += NTHREADS) s_deg[i] = 0;
    for (int i = t; i < NF; i += NTHREADS) s_x[i] = feat[(long long)nb * FD + i];
    __syncthreads();

    // load edges (vectorized int4: 16000 B per block is 16B-aligned), localize,
    // pack into LDS, count degrees
    const int4* __restrict__ src4 = (const int4*)(src + eb);
    const int4* __restrict__ dst4 = (const int4*)(dst + eb);
    for (int i = t; i < EPG / 4; i += NTHREADS) {
        int4 s4 = src4[i];
        int4 d4 = dst4[i];
        int ss[4] = { s4.x - nb, s4.y - nb, s4.z - nb, s4.w - nb };
        int dd[4] = { d4.x - nb, d4.y - nb, d4.z - nb, d4.w - nb };
        #pragma unroll
        for (int k = 0; k < 4; ++k) {
            s_edge[i * 4 + k] = ((unsigned)ss[k] << 16) | (unsigned)dd[k];
            atomicAdd(&s_deg[ss[k]], 1);
            atomicAdd(&s_deg[NPG + dd[k]], 1);
        }
    }
    __syncthreads();

    // norms: rsqrt(max(deg,1))
    for (int i = t; i < NPG; i += NTHREADS) {
        int dو = s_deg[i] > 1 ? s_deg[i] : 1;
        int di = s_deg[NPG + i] > 1 ? s_deg[NPG + i] : 1;
        s_nout[i] = rsqrtf((float)dو);
        s_nin[i] = rsqrtf((float)di);
    }
    // no sync needed here: gconv_layer syncs after zeroing s_agg and before use

    // tiny weights -> registers (uniform, L2-resident across blocks)
    float w1[9], w2[9], bb1[3], bb2[3];
    #pragma unroll
    for (int k = 0; k < 9; ++k) { w1[k] = W1[k]; w2[k] = W2[k]; }
    #pragma unroll
    for (int k = 0; k < 3; ++k) { bb1[k] = b1[k]; bb2[k] = b2[k]; }

    gconv_layer(s_edge, s_nout, s_nin, s_x, s_agg, w1, bb1, t);
    gconv_layer(s_edge, s_nout, s_nin, s_x, s_agg, w2, bb2, t);

    // FC: dot(x_flat[858], Wfc[858]) + bfc, sigmoid
    float partial = 0.f;
    for (int i = t; i < NF; i += NTHREADS) partial += s_x[i] * Wfc[i];
    #pragma unroll
    for (int off = 32; off > 0; off >>= 1) partial += __shfl_down(partial, off, 64);
    if ((t & 63) == 0) s_red[t >> 6] = partial;
    __syncthreads();
    if (t == 0) {
        float tot = s_red[0] + s_red[1] + s_red[2] + s_red[3] + bfc[0];
        out[b] = 1.f / (1.f + expf(-tot));
    }
}

extern "C" void kernel_launch(void* const* d_in, const int* in_sizes, int n_in,
                              void* d_out, int out_size, void* d_ws, size_t ws_size,
                              hipStream_t stream) {
    const float* feat = (const float*)d_in[0];
    const int* src = (const int*)d_in[1];
    const int* dst = (const int*)d_in[2];
    const float* W1 = (const float*)d_in[3];
    const float* b1 = (const float*)d_in[4];
    const float* W2 = (const float*)d_in[5];
    const float* b2 = (const float*)d_in[6];
    const float* Wfc = (const float*)d_in[7];
    const float* bfc = (const float*)d_in[8];
    float* out = (float*)d_out;

    const int B = out_size;  // 8192 graphs
    ppi_fused_kernel<<<B, NTHREADS, 0, stream>>>(feat, src, dst, W1, b1, W2, b2,
                                                 Wfc, bfc, out);
}

// Round 2
// 428.344 us; speedup vs baseline: 2.9326x; 2.9326x over previous
//
#include <hip/hip_runtime.h>

#define NPG 286
#define EPG 4000
#define EPGP 4096          // padded edge slots (256 threads x 16)
#define NT 256
#define NBINS 320          // scan width (multiple of 64), bins 286..319 are zero
#define PADN 287           // pad node id (x4[287] == 0)

// XOR swizzle on 4-dword blocks: kills the 32-way bank conflict of
// stride-64B ds_read_b128 (lane t reads block 4t+r -> banks cycle 0,4,1,5,...)
__device__ __forceinline__ int swz_blk(int j) { return j ^ ((j >> 3) & 7); }
__device__ __forceinline__ int swz_dw(int dw) {
    return (swz_blk(dw >> 2) << 2) | (dw & 3);
}

__device__ __forceinline__ void gconv_layer(
    float4* s_x4, float (*s_agg)[288], const uint4* s_sorted4,
    const int* s_degin, const int* s_degout, int t,
    const float* w, const float* bb, bool scale_out_for_next)
{
    // gather over dst-sorted edges: segmented sum, flush runs with atomics
    {
        float a0 = 0.f, a1 = 0.f, a2 = 0.f;
        int cur = -1;
        #pragma unroll
        for (int r = 0; r < 4; ++r) {
            uint4 e4 = s_sorted4[swz_blk(t * 4 + r)];
            unsigned ee[4] = { e4.x, e4.y, e4.z, e4.w };
            #pragma unroll
            for (int k = 0; k < 4; ++k) {
                int d = (int)(ee[k] >> 16);
                int s = (int)(ee[k] & 0xffffu);
                if (d != cur) {
                    if (cur >= 0) {
                        atomicAdd(&s_agg[0][cur], a0);
                        atomicAdd(&s_agg[1][cur], a1);
                        atomicAdd(&s_agg[2][cur], a2);
                    }
                    cur = d; a0 = a1 = a2 = 0.f;
                }
                float4 xv = s_x4[s];
                a0 += xv.x; a1 += xv.y; a2 += xv.z;
            }
        }
        atomicAdd(&s_agg[0][cur], a0);
        atomicAdd(&s_agg[1][cur], a1);
        atomicAdd(&s_agg[2][cur], a2);
    }
    __syncthreads();
    // combine: agg*nin -> 3x3 matmul -> relu (optionally pre-scale by nout
    // for the NEXT layer's gather), re-zero agg for next use
    for (int v = t; v < NPG; v += NT) {
        int dgi = s_degin[v];
        float ni = rsqrtf((float)(dgi > 1 ? dgi : 1));
        float g0 = s_agg[0][v] * ni, g1 = s_agg[1][v] * ni, g2 = s_agg[2][v] * ni;
        s_agg[0][v] = 0.f; s_agg[1][v] = 0.f; s_agg[2][v] = 0.f;
        float o0 = fmaxf(fmaf(g0, w[0], fmaf(g1, w[3], fmaf(g2, w[6], bb[0]))), 0.f);
        float o1 = fmaxf(fmaf(g0, w[1], fmaf(g1, w[4], fmaf(g2, w[7], bb[1]))), 0.f);
        float o2 = fmaxf(fmaf(g0, w[2], fmaf(g1, w[5], fmaf(g2, w[8], bb[2]))), 0.f);
        if (scale_out_for_next) {
            int dgo = s_degout[v];
            float no = rsqrtf((float)(dgo > 1 ? dgo : 1));
            o0 *= no; o1 *= no; o2 *= no;
        }
        s_x4[v] = make_float4(o0, o1, o2, 0.f);
    }
    __syncthreads();
}

__global__ __launch_bounds__(NT, 5) void ppi_fused2(
    const float* __restrict__ feat,
    const int* __restrict__ src,
    const int* __restrict__ dst,
    const float* __restrict__ W1, const float* __restrict__ b1,
    const float* __restrict__ W2, const float* __restrict__ b2,
    const float* __restrict__ Wfc, const float* __restrict__ bfc,
    float* __restrict__ out)
{
    __shared__ uint4 s_sorted4[EPGP / 4];   // 16384 B, dst-sorted (d<<16)|s
    __shared__ float4 s_x4[288];            // 4608 B, node features (w unused)
    __shared__ float s_agg[3][288];         // 3456 B, plane-per-component
    __shared__ int s_degin[NBINS];          // 1280 B
    __shared__ int s_degout[NBINS];         // 1280 B
    __shared__ int s_cur[NBINS];            // 1280 B (scan result / cursors)
    __shared__ float s_red[4];

    const int b = blockIdx.x, t = threadIdx.x;
    const long long eb = (long long)b * EPG;
    const int nb = b * NPG;

    // ---- phase 1: issue edge loads into registers; zero LDS; feat -> LDS
    unsigned pk[16];
    if (t < 250) {   // 250 * 16 = 4000 edges exactly
        const int4* s4 = (const int4*)(src + eb);
        const int4* d4 = (const int4*)(dst + eb);
        int4 se[4], de[4];
        #pragma unroll
        for (int r = 0; r < 4; ++r) { se[r] = s4[t * 4 + r]; de[r] = d4[t * 4 + r]; }
        #pragma unroll
        for (int r = 0; r < 4; ++r) {
            pk[r * 4 + 0] = ((unsigned)(de[r].x - nb) << 16) | (unsigned)(se[r].x - nb);
            pk[r * 4 + 1] = ((unsigned)(de[r].y - nb) << 16) | (unsigned)(se[r].y - nb);
            pk[r * 4 + 2] = ((unsigned)(de[r].z - nb) << 16) | (unsigned)(se[r].z - nb);
            pk[r * 4 + 3] = ((unsigned)(de[r].w - nb) << 16) | (unsigned)(se[r].w - nb);
        }
    }

    for (int i = t; i < NBINS; i += NT) { s_degin[i] = 0; s_degout[i] = 0; }
    for (int i = t; i < 3 * 288; i += NT) (&s_agg[0][0])[i] = 0.f;
    if (t < 2) s_x4[286 + t] = make_float4(0.f, 0.f, 0.f, 0.f);
    for (int i = EPG + t; i < EPGP; i += NT)
        ((unsigned*)s_sorted4)[swz_dw(i)] = ((unsigned)PADN << 16) | PADN;
    for (int i = t; i < NPG * 3; i += NT) {        // coalesced feat read
        int v = i / 3, c = i - 3 * v;
        ((float*)&s_x4[v])[c] = feat[(long long)nb * 3 + i];
    }

    // tiny weights -> (scalar) regs
    float w1[9], w2[9], bb1[3], bb2[3];
    #pragma unroll
    for (int k = 0; k < 9; ++k) { w1[k] = W1[k]; w2[k] = W2[k]; }
    #pragma unroll
    for (int k = 0; k < 3; ++k) { bb1[k] = b1[k]; bb2[k] = b2[k]; }

    __syncthreads();

    // ---- phase 2: degree histograms (one-time atomics, from registers)
    if (t < 250) {
        #pragma unroll
        for (int k = 0; k < 16; ++k) {
            atomicAdd(&s_degout[pk[k] & 0xffffu], 1);
            atomicAdd(&s_degin[pk[k] >> 16], 1);
        }
    }
    __syncthreads();

    // ---- phase 3: exclusive prefix scan of deg_in -> cursors (wave 0)
    if (t < 64) {
        int run = 0;
        #pragma unroll
        for (int c = 0; c < NBINS; c += 64) {
            int v = s_degin[c + t];
            int inc = v;
            #pragma unroll
            for (int o = 1; o < 64; o <<= 1) {
                int up = __shfl_up(inc, o, 64);
                if (t >= o) inc += up;
            }
            s_cur[c + t] = run + inc - v;
            run += __shfl(inc, 63, 64);
        }
    }
    __syncthreads();

    // ---- phase 4: counting-sort placement (dst-sorted edge array)
    if (t < 250) {
        #pragma unroll
        for (int k = 0; k < 16; ++k) {
            int pos = atomicAdd(&s_cur[pk[k] >> 16], 1);
            ((unsigned*)s_sorted4)[swz_dw(pos)] = pk[k];
        }
    }
    __syncthreads();

    // ---- phase 5: scale feat by norm_out (layer-1 input)
    for (int v = t; v < NPG; v += NT) {
        int dg = s_degout[v];
        float no = rsqrtf((float)(dg > 1 ? dg : 1));
        float4 xv = s_x4[v];
        xv.x *= no; xv.y *= no; xv.z *= no; xv.w = 0.f;
        s_x4[v] = xv;
    }
    __syncthreads();

    // ---- layers (layer 1 pre-scales its output by norm_out for layer 2)
    gconv_layer(s_x4, s_agg, s_sorted4, s_degin, s_degout, t, w1, bb1, true);
    gconv_layer(s_x4, s_agg, s_sorted4, s_degin, s_degout, t, w2, bb2, false);

    // ---- FC + sigmoid
    float partial = 0.f;
    for (int v = t; v < NPG; v += NT) {
        float4 xv = s_x4[v];
        const float* wv = Wfc + 3 * v;
        partial = fmaf(xv.x, wv[0], fmaf(xv.y, wv[1], fmaf(xv.z, wv[2], partial)));
    }
    #pragma unroll
    for (int off = 32; off > 0; off >>= 1) partial += __shfl_down(partial, off, 64);
    if ((t & 63) == 0) s_red[t >> 6] = partial;
    __syncthreads();
    if (t == 0) {
        float tot = s_red[0] + s_red[1] + s_red[2] + s_red[3] + bfc[0];
        out[b] = 1.f / (1.f + expf(-tot));
    }
}

extern "C" void kernel_launch(void* const* d_in, const int* in_sizes, int n_in,
                              void* d_out, int out_size, void* d_ws, size_t ws_size,
                              hipStream_t stream) {
    const float* feat = (const float*)d_in[0];
    const int* src = (const int*)d_in[1];
    const int* dst = (const int*)d_in[2];
    const float* W1 = (const float*)d_in[3];
    const float* b1 = (const float*)d_in[4];
    const float* W2 = (const float*)d_in[5];
    const float* b2 = (const float*)d_in[6];
    const float* Wfc = (const float*)d_in[7];
    const float* bfc = (const float*)d_in[8];
    float* out = (float*)d_out;

    const int B = out_size;  // 8192 graphs
    ppi_fused2<<<B, NT, 0, stream>>>(feat, src, dst, W1, b1, W2, b2, Wfc, bfc, out);
}